// Round 2
// baseline (614.022 us; speedup 1.0000x reference)
//
#include <hip/hip_runtime.h>
#include <hip/hip_bf16.h>

// FrameOTAMDistanceNetwork, round 2: one wave (64 threads) per (s,b) pair.
// All-register design: no LDS, no __syncthreads. Lane l owns float4 slice
// (c*64+l) of every frame -> fully coalesced 1KB/wave-instr global loads.
// acc[8][8] + norms in registers; 6-step shfl_xor butterfly reduction;
// both soft-DPs fully unrolled per-lane with HW exp/log.
// Memory-bound: 436 MB compulsory -> ~70us floor at 6.3 TB/s.

constexpr int kNF   = 8;
constexpr int kSeq  = 25;
constexpr int kBS   = 256;
constexpr int kDF   = 16384;
constexpr float kLam    = 0.1f;
constexpr float kInvLam = 10.0f;

__global__ __launch_bounds__(64, 2) void otam_kernel(
    const float* __restrict__ sv,   // [Seq, BS, DF]
    const float* __restrict__ tv,   // [BS, DF]
    float* __restrict__ out)        // [Seq, BS]
{
    const int bid = blockIdx.x;
    const int b = bid % kBS;        // s-major: consecutive blocks stream
    const int s = bid / kBS;        //          contiguous sv (and tv) slices
    const int l = threadIdx.x;      // 0..63

    const float4* __restrict__ U = (const float4*)(sv + ((size_t)s * kBS + b) * kDF);
    const float4* __restrict__ V = (const float4*)(tv + (size_t)b * kDF);
    // frame f occupies float4 indices [f*512, (f+1)*512)

    float acc[kNF][kNF] = {};
    float un[kNF] = {};
    float vn[kNF] = {};

    #pragma unroll 2
    for (int c = 0; c < 8; ++c) {
        float4 vv[kNF], uu[kNF];
        #pragma unroll
        for (int j = 0; j < kNF; ++j) vv[j] = V[j * 512 + c * 64 + l];
        #pragma unroll
        for (int i = 0; i < kNF; ++i) uu[i] = U[i * 512 + c * 64 + l];

        #pragma unroll
        for (int i = 0; i < kNF; ++i)
            un[i] = fmaf(uu[i].x, uu[i].x, fmaf(uu[i].y, uu[i].y,
                    fmaf(uu[i].z, uu[i].z, fmaf(uu[i].w, uu[i].w, un[i]))));
        #pragma unroll
        for (int j = 0; j < kNF; ++j)
            vn[j] = fmaf(vv[j].x, vv[j].x, fmaf(vv[j].y, vv[j].y,
                    fmaf(vv[j].z, vv[j].z, fmaf(vv[j].w, vv[j].w, vn[j]))));
        #pragma unroll
        for (int i = 0; i < kNF; ++i)
            #pragma unroll
            for (int j = 0; j < kNF; ++j)
                acc[i][j] = fmaf(uu[i].x, vv[j].x, fmaf(uu[i].y, vv[j].y,
                            fmaf(uu[i].z, vv[j].z, fmaf(uu[i].w, vv[j].w, acc[i][j]))));
    }

    // ---- butterfly reduction of 80 values across the 64-lane wave ----
    #pragma unroll
    for (int m = 32; m >= 1; m >>= 1) {
        #pragma unroll
        for (int i = 0; i < kNF; ++i) {
            un[i] += __shfl_xor(un[i], m, 64);
            vn[i] += __shfl_xor(vn[i], m, 64);
        }
        #pragma unroll
        for (int i = 0; i < kNF; ++i)
            #pragma unroll
            for (int j = 0; j < kNF; ++j)
                acc[i][j] += __shfl_xor(acc[i][j], m, 64);
    }

    // ---- normalize: D[i][j] = cos(u_i, v_j); every lane holds all 64 ----
    float ru[kNF], rv[kNF];
    #pragma unroll
    for (int i = 0; i < kNF; ++i) { ru[i] = rsqrtf(un[i]); rv[i] = rsqrtf(vn[i]); }
    float D[kNF][kNF];
    #pragma unroll
    for (int i = 0; i < kNF; ++i)
        #pragma unroll
        for (int j = 0; j < kNF; ++j)
            D[i][j] = acc[i][j] * ru[i] * rv[j];

    // ---- two soft-DPs, fully unrolled in registers (redundant per lane) ----
    auto lse2 = [](float a, float bb) {
        float mx = fmaxf(a, bb), mn = fminf(a, bb);
        return mx + kLam * __logf(1.f + __expf((mn - mx) * kInvLam));
    };

    float res[2];
    #pragma unroll
    for (int t = 0; t < 2; ++t) {
        float prev[kNF];
        #pragma unroll
        for (int r = 0; r < kNF; ++r) prev[r] = t ? D[0][r] : D[r][0];
        #pragma unroll
        for (int i = 1; i < kNF; ++i) {
            #pragma unroll
            for (int r = kNF - 1; r >= 1; --r)
                prev[r] = lse2(prev[r - 1], prev[r]) + (t ? D[i][r] : D[r][i]);
            prev[0] += (t ? D[i][0] : D[0][i]);
        }
        float mx = prev[0];
        #pragma unroll
        for (int r = 1; r < kNF; ++r) mx = fmaxf(mx, prev[r]);
        float e = 0.f;
        #pragma unroll
        for (int r = 0; r < kNF; ++r) e += __expf((prev[r] - mx) * kInvLam);
        res[t] = mx + kLam * __logf(e);
    }

    if (l == 0) out[(size_t)s * kBS + b] = 0.5f * (res[0] + res[1]);
}

extern "C" void kernel_launch(void* const* d_in, const int* in_sizes, int n_in,
                              void* d_out, int out_size, void* d_ws, size_t ws_size,
                              hipStream_t stream) {
    const float* sv = (const float*)d_in[0];
    const float* tv = (const float*)d_in[1];
    float* out = (float*)d_out;
    otam_kernel<<<dim3(kSeq * kBS), dim3(64), 0, stream>>>(sv, tv, out);
}